// Round 9
// baseline (411.829 us; speedup 1.0000x reference)
//
#include <hip/hip_runtime.h>
#include <hip/hip_bf16.h>

#define N_NODES 10000
#define N_EDGES 320000
#define DIM     256
#define N_LAYERS 5
#define N_GRAPHS 128
#define RWSE_K  16
#define GBM 32

typedef __bf16 bf16_t;
typedef bf16_t bf16x8 __attribute__((ext_vector_type(8)));
typedef float  f32x4  __attribute__((ext_vector_type(4)));

__device__ inline ushort f2bf(float f) {
    union { float f; unsigned u; } v; v.f = f;
    unsigned r = v.u + 0x7fff + ((v.u >> 16) & 1);
    return (ushort)(r >> 16);
}
__device__ inline float bfbits2f(unsigned hi16) {
    union { unsigned u; float f; } v; v.u = hi16;
    return v.f;
}

// ---------------- fused setup: embed + edge-count + weight conv + BN fold ----
__global__ __launch_bounds__(256)
void setup_kernel(const int* __restrict__ feat_id,
                  const float* __restrict__ rwse,
                  const int* __restrict__ in_deg,
                  const float* __restrict__ w_val,
                  const float* __restrict__ b_val,
                  const float* __restrict__ w_rwse,
                  const float* __restrict__ b_rwse,
                  const float* __restrict__ deg_emb,
                  ushort* __restrict__ hb,
                  const int* __restrict__ ei, int* __restrict__ cnt_arr,
                  const float* __restrict__ w1, const float* __restrict__ w2,
                  ushort* __restrict__ wt1, ushort* __restrict__ wt2,
                  const float* __restrict__ gamma, const float* __restrict__ beta,
                  const float* __restrict__ mean, const float* __restrict__ var,
                  const float* __restrict__ b2, float* __restrict__ scale,
                  float* __restrict__ shift) {
    __shared__ float r[RWSE_K];
    __shared__ float t[32][33];
    int b = blockIdx.x;
    int tid = threadIdx.x;
    if (b < N_NODES) {
        int i = b, d = tid;
        if (d < RWSE_K) r[d] = rwse[i * RWSE_K + d];
        __syncthreads();
        int hid = feat_id[i] & (DIM - 1);
        int dg = in_deg[i];
        dg = dg < 0 ? 0 : (dg > 1000 ? 1000 : dg);
        float v = w_val[hid * DIM + d] + b_val[d] + b_rwse[d] + deg_emb[dg * DIM + d];
#pragma unroll
        for (int k = 0; k < RWSE_K; ++k) v += r[k] * w_rwse[k * DIM + d];
        hb[i * DIM + d] = f2bf(v);
    } else if (b < 11250) {
        int e = (b - N_NODES) * 256 + tid;
        if (e < N_EDGES) atomicAdd(&cnt_arr[ei[N_EDGES + e]], 1);
    } else if (b < 11890) {
        int w_id = b - 11250;
        int l = w_id >> 7;
        int rem = w_id & 127;
        int mat = rem >> 6;
        int tile = rem & 63;
        const float* W  = (mat ? w2  : w1)  + (size_t)l * DIM * DIM;
        ushort*      Wt = (mat ? wt2 : wt1) + (size_t)l * DIM * DIM;
        int k0 = (tile >> 3) * 32, n0 = (tile & 7) * 32;
        int tx = tid & 31, ty = tid >> 5;
#pragma unroll
        for (int j = 0; j < 4; ++j)
            t[ty + j * 8][tx] = W[(k0 + ty + j * 8) * DIM + n0 + tx];
        __syncthreads();
#pragma unroll
        for (int j = 0; j < 4; ++j)
            Wt[(n0 + ty + j * 8) * DIM + k0 + tx] = f2bf(t[tx][ty + j * 8]);
    } else {
        int l = b - 11890;
        int idx = l * DIM + tid;
        float s = gamma[idx] * rsqrtf(var[idx] + 1e-5f);
        scale[idx] = s;
        shift[idx] = beta[idx] + (b2[idx] - mean[idx]) * s;
    }
}

// exclusive scan of cnt_arr into cur (single block, wave-shuffle based)
__global__ __launch_bounds__(1024)
void scan_kernel(const int* __restrict__ cnt_arr, int* __restrict__ cur, int n) {
    __shared__ int wsum[16];
    __shared__ int carry_sh;
    int tid = threadIdx.x, wave = tid >> 6, lane = tid & 63;
    if (tid == 0) carry_sh = 0;
    __syncthreads();
    for (int base = 0; base < n; base += 1024) {
        int idx = base + tid;
        int v = (idx < n) ? cnt_arr[idx] : 0;
        int s = v;
#pragma unroll
        for (int off = 1; off < 64; off <<= 1) {
            int t = __shfl_up(s, off, 64);
            if (lane >= off) s += t;
        }
        if (lane == 63) wsum[wave] = s;
        __syncthreads();
        if (wave == 0) {
            int ws = (lane < 16) ? wsum[lane] : 0;
#pragma unroll
            for (int off = 1; off < 16; off <<= 1) {
                int t = __shfl_up(ws, off, 64);
                if (lane >= off) ws += t;
            }
            if (lane < 16) wsum[lane] = ws;
        }
        __syncthreads();
        int excl = s - v + (wave ? wsum[wave - 1] : 0) + carry_sh;
        if (idx < n) cur[idx] = excl;
        __syncthreads();
        if (tid == 0) carry_sh += wsum[15];
        __syncthreads();
    }
}

__global__ __launch_bounds__(256)
void fill_kernel(const int* __restrict__ ei, int* __restrict__ cur,
                 int* __restrict__ cs) {
    int e = blockIdx.x * 256 + threadIdx.x;
    if (e < N_EDGES) {
        int d = ei[N_EDGES + e];
        int p = atomicAdd(&cur[d], 1);
        cs[p] = ei[e];
    }
}

// ---------------- fused layer: agg (gather) + MLP (2x MFMA GEMM) ------------
// Block = 32 rows. Phase 1: each wave gathers neighbor sums for 8 nodes into
// the shared A/T tile (AT). Phase 2/3: R5-proven GEMM1/GEMM2 with W staged
// per k-step from L2. hb double-buffered across layers (read hb_in, write
// hb_out) to avoid cross-block races. 37.4 KB LDS -> 4 blocks/CU.
#define ACCV(v)                                                        \
    acc[0] += bfbits2f((v).x << 16); acc[1] += bfbits2f((v).x & 0xffff0000u); \
    acc[2] += bfbits2f((v).y << 16); acc[3] += bfbits2f((v).y & 0xffff0000u); \
    acc[4] += bfbits2f((v).z << 16); acc[5] += bfbits2f((v).z & 0xffff0000u); \
    acc[6] += bfbits2f((v).w << 16); acc[7] += bfbits2f((v).w & 0xffff0000u);

__global__ __launch_bounds__(256)
void layer_kernel(const ushort* __restrict__ hb_in, ushort* __restrict__ hb_out,
                  float* __restrict__ outF,
                  const int* __restrict__ cur, const int* __restrict__ cs,
                  const float* __restrict__ eps_gin, int layer,
                  const ushort* __restrict__ Wt1, const float* __restrict__ b1,
                  const ushort* __restrict__ Wt2,
                  const float* __restrict__ bnsc, const float* __restrict__ bnsh,
                  int nrows) {
    __shared__ __align__(16) ushort AT[GBM][DIM + 8];   // A tile, then T tile
    __shared__ __align__(16) ushort Bs[DIM][40];
    int tx = threadIdx.x;
    int row0 = blockIdx.x * GBM;
    int wave = tx >> 6, lane = tx & 63, half = lane >> 5, sl = lane & 31;
    int quad = lane >> 4, l16 = lane & 15;
    const uint4* hb4 = (const uint4*)hb_in;   // row = 32 uint4
    float sc = 1.0f + eps_gin[layer];

    // ---- phase 1: gather 8 nodes per wave into AT ----
    for (int j = 0; j < 8; ++j) {
        int i = row0 + wave * 8 + j;
        if (i >= nrows) break;
        float acc[8];
#pragma unroll
        for (int t = 0; t < 8; ++t) acc[t] = 0.f;
        int e0 = i ? cur[i - 1] : 0;
        int e1 = cur[i];
        for (int base = e0; base < e1; base += 64) {
            int rem = e1 - base;
            int cnt = rem < 64 ? rem : 64;
            int idx = (base + lane < e1) ? cs[base + lane] : 0;
            int jj = 0;
            for (; jj + 8 <= cnt; jj += 8) {
                int s0 = __shfl(idx, jj + half, 64);
                int s1 = __shfl(idx, jj + 2 + half, 64);
                int s2 = __shfl(idx, jj + 4 + half, 64);
                int s3 = __shfl(idx, jj + 6 + half, 64);
                uint4 v0 = hb4[(size_t)s0 * 32 + sl];
                uint4 v1 = hb4[(size_t)s1 * 32 + sl];
                uint4 v2 = hb4[(size_t)s2 * 32 + sl];
                uint4 v3 = hb4[(size_t)s3 * 32 + sl];
                ACCV(v0); ACCV(v1); ACCV(v2); ACCV(v3);
            }
            for (; jj + 2 <= cnt; jj += 2) {
                int s = __shfl(idx, jj + half, 64);
                uint4 v = hb4[(size_t)s * 32 + sl];
                ACCV(v);
            }
            if (jj < cnt) {
                int s = __shfl(idx, jj, 64);
                if (half == 0) {
                    uint4 v = hb4[(size_t)s * 32 + sl];
                    ACCV(v);
                }
            }
        }
#pragma unroll
        for (int t = 0; t < 8; ++t) acc[t] += __shfl_xor(acc[t], 32, 64);
        if (half == 0) {
            uint4 sv = hb4[(size_t)i * 32 + sl];   // self term (bf16)
            acc[0] += bfbits2f(sv.x << 16) * sc; acc[1] += bfbits2f(sv.x & 0xffff0000u) * sc;
            acc[2] += bfbits2f(sv.y << 16) * sc; acc[3] += bfbits2f(sv.y & 0xffff0000u) * sc;
            acc[4] += bfbits2f(sv.z << 16) * sc; acc[5] += bfbits2f(sv.z & 0xffff0000u) * sc;
            acc[6] += bfbits2f(sv.w << 16) * sc; acc[7] += bfbits2f(sv.w & 0xffff0000u) * sc;
            uint4 o;
            o.x = (uint)f2bf(acc[0]) | ((uint)f2bf(acc[1]) << 16);
            o.y = (uint)f2bf(acc[2]) | ((uint)f2bf(acc[3]) << 16);
            o.z = (uint)f2bf(acc[4]) | ((uint)f2bf(acc[5]) << 16);
            o.w = (uint)f2bf(acc[6]) | ((uint)f2bf(acc[7]) << 16);
            *(uint4*)&AT[wave * 8 + j][sl * 8] = o;
        }
    }
    __syncthreads();

    // ---- phase 2: GEMM1 t = relu(A@W1 + b1) ----
    int wr = (wave >> 1) * 16;
    int wc = (wave & 1) * 128;
    int srow = tx >> 2;
    int skol = (tx & 3) * 8;
    f32x4 acc4[8];
#pragma unroll
    for (int t = 0; t < 8; ++t) acc4[t] = (f32x4){0.f, 0.f, 0.f, 0.f};
    for (int k0 = 0; k0 < DIM; k0 += 32) {
#pragma unroll
        for (int jj = 0; jj < 4; ++jj) {
            int r = srow + 64 * jj;
            *(uint4*)&Bs[r][skol] = *(const uint4*)&Wt1[(size_t)r * DIM + k0 + skol];
        }
        __syncthreads();
        bf16x8 af = *(const bf16x8*)&AT[wr + l16][k0 + quad * 8];
#pragma unroll
        for (int tj = 0; tj < 8; ++tj) {
            bf16x8 bf = *(const bf16x8*)&Bs[wc + tj * 16 + l16][quad * 8];
            acc4[tj] = __builtin_amdgcn_mfma_f32_16x16x32_bf16(af, bf, acc4[tj], 0, 0, 0);
        }
        __syncthreads();
    }
    // write T into AT (all A reads completed at the last barrier)
#pragma unroll
    for (int tj = 0; tj < 8; ++tj) {
        int col = wc + tj * 16 + l16;
        float bias = b1[col];
#pragma unroll
        for (int r = 0; r < 4; ++r)
            AT[wr + quad * 4 + r][col] = f2bf(fmaxf(acc4[tj][r] + bias, 0.f));
    }
    __syncthreads();

    // ---- phase 3: GEMM2 h = relu(bn(T@W2)) ----
#pragma unroll
    for (int t = 0; t < 8; ++t) acc4[t] = (f32x4){0.f, 0.f, 0.f, 0.f};
    for (int k0 = 0; k0 < DIM; k0 += 32) {
#pragma unroll
        for (int jj = 0; jj < 4; ++jj) {
            int r = srow + 64 * jj;
            *(uint4*)&Bs[r][skol] = *(const uint4*)&Wt2[(size_t)r * DIM + k0 + skol];
        }
        __syncthreads();
        bf16x8 af = *(const bf16x8*)&AT[wr + l16][k0 + quad * 8];
#pragma unroll
        for (int tj = 0; tj < 8; ++tj) {
            bf16x8 bf = *(const bf16x8*)&Bs[wc + tj * 16 + l16][quad * 8];
            acc4[tj] = __builtin_amdgcn_mfma_f32_16x16x32_bf16(af, bf, acc4[tj], 0, 0, 0);
        }
        __syncthreads();
    }
#pragma unroll
    for (int tj = 0; tj < 8; ++tj) {
        int col = wc + tj * 16 + l16;
        float s = bnsc[col], sh = bnsh[col];
#pragma unroll
        for (int r = 0; r < 4; ++r) {
            int row = row0 + wr + quad * 4 + r;
            if (row < nrows) {
                float v = fmaxf(acc4[tj][r] * s + sh, 0.f);
                if (outF) outF[(size_t)row * DIM + col] = v;
                if (hb_out) hb_out[(size_t)row * DIM + col] = f2bf(v);
            }
        }
    }
}

// ---------------- pooling: batch sorted -> per-graph contiguous range -------
__global__ __launch_bounds__(256)
void pool_kernel(const float* __restrict__ hfin, const int* __restrict__ batch,
                 float* __restrict__ out) {
    int g = blockIdx.x;
    int d = threadIdx.x;
    int l = 0, r = N_NODES;
    while (l < r) { int m = (l + r) >> 1; if (batch[m] < g) l = m + 1; else r = m; }
    int lo = l;
    r = N_NODES;
    while (l < r) { int m = (l + r) >> 1; if (batch[m] < g + 1) l = m + 1; else r = m; }
    int hi = l;
    float a0 = 0.f, a1 = 0.f, a2 = 0.f, a3 = 0.f;
    int i = lo;
    for (; i + 4 <= hi; i += 4) {
        a0 += hfin[(size_t)i * DIM + d];
        a1 += hfin[(size_t)(i + 1) * DIM + d];
        a2 += hfin[(size_t)(i + 2) * DIM + d];
        a3 += hfin[(size_t)(i + 3) * DIM + d];
    }
    for (; i < hi; ++i) a0 += hfin[(size_t)i * DIM + d];
    float c = (float)(hi - lo);
    if (c < 1.f) c = 1.f;
    out[g * DIM + d] = ((a0 + a1) + (a2 + a3)) / c;
}

// ---------------- launch ----------------
extern "C" void kernel_launch(void* const* d_in, const int* in_sizes, int n_in,
                              void* d_out, int out_size, void* d_ws, size_t ws_size,
                              hipStream_t stream) {
    const int*   feat_id  = (const int*)d_in[0];
    const int*   ei       = (const int*)d_in[1];
    const int*   batch    = (const int*)d_in[2];
    const float* rwse     = (const float*)d_in[3];
    const int*   in_deg   = (const int*)d_in[4];
    const float* w_val    = (const float*)d_in[5];
    const float* b_val    = (const float*)d_in[6];
    const float* w_rwse   = (const float*)d_in[7];
    const float* b_rwse   = (const float*)d_in[8];
    const float* deg_emb  = (const float*)d_in[9];
    const float* mlp_w1   = (const float*)d_in[10];
    const float* mlp_b1   = (const float*)d_in[11];
    const float* mlp_w2   = (const float*)d_in[12];
    const float* mlp_b2   = (const float*)d_in[13];
    const float* bn_gamma = (const float*)d_in[14];
    const float* bn_beta  = (const float*)d_in[15];
    const float* bn_mean  = (const float*)d_in[16];
    const float* bn_var   = (const float*)d_in[17];
    const float* eps_gin  = (const float*)d_in[18];

    float* out = (float*)d_out;
    float* out_h = out + N_GRAPHS * DIM;   // final h (f32) written by last layer

    char* w = (char*)d_ws;
    ushort* hbA  = (ushort*)w;                                // N*D bf16
    ushort* hbB  = hbA + (size_t)N_NODES * DIM;               // N*D bf16
    ushort* wt1  = hbB + (size_t)N_NODES * DIM;               // L*D*D bf16
    ushort* wt2  = wt1 + (size_t)N_LAYERS * DIM * DIM;        // L*D*D bf16
    int* cnt_arr = (int*)(wt2 + (size_t)N_LAYERS * DIM * DIM); // N
    int* cur     = cnt_arr + N_NODES;                         // N
    int* cs      = cur + N_NODES;                             // E
    float* bnsc  = (float*)(cs + N_EDGES);                    // L*D
    float* bnsh  = bnsc + N_LAYERS * DIM;                     // L*D

    hipMemsetAsync(cnt_arr, 0, N_NODES * sizeof(int), stream);

    setup_kernel<<<11895, 256, 0, stream>>>(
        feat_id, rwse, in_deg, w_val, b_val, w_rwse, b_rwse, deg_emb,
        hbA, ei, cnt_arr, mlp_w1, mlp_w2, wt1, wt2,
        bn_gamma, bn_beta, bn_mean, bn_var, mlp_b2, bnsc, bnsh);
    scan_kernel<<<1, 1024, 0, stream>>>(cnt_arr, cur, N_NODES);
    fill_kernel<<<(N_EDGES + 255) / 256, 256, 0, stream>>>(ei, cur, cs);

    int ggrid = (N_NODES + GBM - 1) / GBM;
    ushort* hin = hbA;
    ushort* hout = hbB;
    for (int l = 0; l < N_LAYERS; ++l) {
        bool last = (l == N_LAYERS - 1);
        layer_kernel<<<ggrid, 256, 0, stream>>>(
            hin, last ? nullptr : hout, last ? out_h : nullptr,
            cur, cs, eps_gin, l,
            wt1 + (size_t)l * DIM * DIM, mlp_b1 + l * DIM,
            wt2 + (size_t)l * DIM * DIM,
            bnsc + l * DIM, bnsh + l * DIM, N_NODES);
        ushort* tmp = hin; hin = hout; hout = tmp;
    }

    pool_kernel<<<N_GRAPHS, 256, 0, stream>>>(out_h, batch, out);
}

// Round 10
// 342.674 us; speedup vs baseline: 1.2018x; 1.2018x over previous
//
#include <hip/hip_runtime.h>
#include <hip/hip_bf16.h>

#define N_NODES 10000
#define N_EDGES 320000
#define DIM     256
#define N_LAYERS 5
#define N_GRAPHS 128
#define RWSE_K  16
#define GBM 16

typedef __bf16 bf16_t;
typedef bf16_t bf16x8 __attribute__((ext_vector_type(8)));
typedef float  f32x4  __attribute__((ext_vector_type(4)));

__device__ inline ushort f2bf(float f) {
    union { float f; unsigned u; } v; v.f = f;
    unsigned r = v.u + 0x7fff + ((v.u >> 16) & 1);
    return (ushort)(r >> 16);
}
__device__ inline float bfbits2f(unsigned hi16) {
    union { unsigned u; float f; } v; v.u = hi16;
    return v.f;
}

// ---------------- fused setup: embed + edge-count + weight conv + BN fold ----
__global__ __launch_bounds__(256)
void setup_kernel(const int* __restrict__ feat_id,
                  const float* __restrict__ rwse,
                  const int* __restrict__ in_deg,
                  const float* __restrict__ w_val,
                  const float* __restrict__ b_val,
                  const float* __restrict__ w_rwse,
                  const float* __restrict__ b_rwse,
                  const float* __restrict__ deg_emb,
                  ushort* __restrict__ hb,
                  const int* __restrict__ ei, int* __restrict__ cnt_arr,
                  const float* __restrict__ w1, const float* __restrict__ w2,
                  ushort* __restrict__ wt1, ushort* __restrict__ wt2,
                  const float* __restrict__ gamma, const float* __restrict__ beta,
                  const float* __restrict__ mean, const float* __restrict__ var,
                  const float* __restrict__ b2, float* __restrict__ scale,
                  float* __restrict__ shift) {
    __shared__ float r[RWSE_K];
    __shared__ float t[32][33];
    int b = blockIdx.x;
    int tid = threadIdx.x;
    if (b < N_NODES) {
        int i = b, d = tid;
        if (d < RWSE_K) r[d] = rwse[i * RWSE_K + d];
        __syncthreads();
        int hid = feat_id[i] & (DIM - 1);
        int dg = in_deg[i];
        dg = dg < 0 ? 0 : (dg > 1000 ? 1000 : dg);
        float v = w_val[hid * DIM + d] + b_val[d] + b_rwse[d] + deg_emb[dg * DIM + d];
#pragma unroll
        for (int k = 0; k < RWSE_K; ++k) v += r[k] * w_rwse[k * DIM + d];
        hb[i * DIM + d] = f2bf(v);
    } else if (b < 11250) {
        int e = (b - N_NODES) * 256 + tid;
        if (e < N_EDGES) atomicAdd(&cnt_arr[ei[N_EDGES + e]], 1);
    } else if (b < 11890) {
        int w_id = b - 11250;
        int l = w_id >> 7;
        int rem = w_id & 127;
        int mat = rem >> 6;
        int tile = rem & 63;
        const float* W  = (mat ? w2  : w1)  + (size_t)l * DIM * DIM;
        ushort*      Wt = (mat ? wt2 : wt1) + (size_t)l * DIM * DIM;
        int k0 = (tile >> 3) * 32, n0 = (tile & 7) * 32;
        int tx = tid & 31, ty = tid >> 5;
#pragma unroll
        for (int j = 0; j < 4; ++j)
            t[ty + j * 8][tx] = W[(k0 + ty + j * 8) * DIM + n0 + tx];
        __syncthreads();
#pragma unroll
        for (int j = 0; j < 4; ++j)
            Wt[(n0 + ty + j * 8) * DIM + k0 + tx] = f2bf(t[tx][ty + j * 8]);
    } else {
        int l = b - 11890;
        int idx = l * DIM + tid;
        float s = gamma[idx] * rsqrtf(var[idx] + 1e-5f);
        scale[idx] = s;
        shift[idx] = beta[idx] + (b2[idx] - mean[idx]) * s;
    }
}

// exclusive scan of cnt_arr into cur (single block, wave-shuffle based)
__global__ __launch_bounds__(1024)
void scan_kernel(const int* __restrict__ cnt_arr, int* __restrict__ cur, int n) {
    __shared__ int wsum[16];
    __shared__ int carry_sh;
    int tid = threadIdx.x, wave = tid >> 6, lane = tid & 63;
    if (tid == 0) carry_sh = 0;
    __syncthreads();
    for (int base = 0; base < n; base += 1024) {
        int idx = base + tid;
        int v = (idx < n) ? cnt_arr[idx] : 0;
        int s = v;
#pragma unroll
        for (int off = 1; off < 64; off <<= 1) {
            int t = __shfl_up(s, off, 64);
            if (lane >= off) s += t;
        }
        if (lane == 63) wsum[wave] = s;
        __syncthreads();
        if (wave == 0) {
            int ws = (lane < 16) ? wsum[lane] : 0;
#pragma unroll
            for (int off = 1; off < 16; off <<= 1) {
                int t = __shfl_up(ws, off, 64);
                if (lane >= off) ws += t;
            }
            if (lane < 16) wsum[lane] = ws;
        }
        __syncthreads();
        int excl = s - v + (wave ? wsum[wave - 1] : 0) + carry_sh;
        if (idx < n) cur[idx] = excl;
        __syncthreads();
        if (tid == 0) carry_sh += wsum[15];
        __syncthreads();
    }
}

__global__ __launch_bounds__(256)
void fill_kernel(const int* __restrict__ ei, int* __restrict__ cur,
                 int* __restrict__ cs) {
    int e = blockIdx.x * 256 + threadIdx.x;
    if (e < N_EDGES) {
        int d = ei[N_EDGES + e];
        int p = atomicAdd(&cur[d], 1);
        cs[p] = ei[e];
    }
}

// ---------------- aggregation (R5-proven; self-term from bf16 hb) -----------
#define ACCV(v)                                                        \
    acc[0] += bfbits2f((v).x << 16); acc[1] += bfbits2f((v).x & 0xffff0000u); \
    acc[2] += bfbits2f((v).y << 16); acc[3] += bfbits2f((v).y & 0xffff0000u); \
    acc[4] += bfbits2f((v).z << 16); acc[5] += bfbits2f((v).z & 0xffff0000u); \
    acc[6] += bfbits2f((v).w << 16); acc[7] += bfbits2f((v).w & 0xffff0000u);

__global__ __launch_bounds__(256)
void agg_kernel(const ushort* __restrict__ hb,
                const int* __restrict__ cur, const int* __restrict__ cs,
                const float* __restrict__ eps_gin, int layer,
                ushort* __restrict__ y) {
    int wave = threadIdx.x >> 6;
    int lane = threadIdx.x & 63;
    int half = lane >> 5;
    int sl   = lane & 31;
    int i = blockIdx.x * 4 + wave;
    if (i >= N_NODES) return;
    const uint4* hb4 = (const uint4*)hb;   // row = 32 uint4
    float acc[8];
#pragma unroll
    for (int t = 0; t < 8; ++t) acc[t] = 0.f;

    int e0 = i ? cur[i - 1] : 0;
    int e1 = cur[i];
    for (int base = e0; base < e1; base += 64) {
        int rem = e1 - base;
        int cnt = rem < 64 ? rem : 64;
        int idx = (base + lane < e1) ? cs[base + lane] : 0;
        int j = 0;
        for (; j + 8 <= cnt; j += 8) {
            int s0 = __shfl(idx, j + half, 64);
            int s1 = __shfl(idx, j + 2 + half, 64);
            int s2 = __shfl(idx, j + 4 + half, 64);
            int s3 = __shfl(idx, j + 6 + half, 64);
            uint4 v0 = hb4[(size_t)s0 * 32 + sl];
            uint4 v1 = hb4[(size_t)s1 * 32 + sl];
            uint4 v2 = hb4[(size_t)s2 * 32 + sl];
            uint4 v3 = hb4[(size_t)s3 * 32 + sl];
            ACCV(v0); ACCV(v1); ACCV(v2); ACCV(v3);
        }
        for (; j + 2 <= cnt; j += 2) {
            int s = __shfl(idx, j + half, 64);
            uint4 v = hb4[(size_t)s * 32 + sl];
            ACCV(v);
        }
        if (j < cnt) {
            int s = __shfl(idx, j, 64);
            if (half == 0) {
                uint4 v = hb4[(size_t)s * 32 + sl];
                ACCV(v);
            }
        }
    }
#pragma unroll
    for (int t = 0; t < 8; ++t) acc[t] += __shfl_xor(acc[t], 32, 64);
    if (half == 0) {
        float sc = 1.0f + eps_gin[layer];
        uint4 sv = hb4[(size_t)i * 32 + sl];   // self term (bf16)
        acc[0] += bfbits2f(sv.x << 16) * sc; acc[1] += bfbits2f(sv.x & 0xffff0000u) * sc;
        acc[2] += bfbits2f(sv.y << 16) * sc; acc[3] += bfbits2f(sv.y & 0xffff0000u) * sc;
        acc[4] += bfbits2f(sv.z << 16) * sc; acc[5] += bfbits2f(sv.z & 0xffff0000u) * sc;
        acc[6] += bfbits2f(sv.w << 16) * sc; acc[7] += bfbits2f(sv.w & 0xffff0000u) * sc;
        uint4 o;
        o.x = (uint)f2bf(acc[0]) | ((uint)f2bf(acc[1]) << 16);
        o.y = (uint)f2bf(acc[2]) | ((uint)f2bf(acc[3]) << 16);
        o.z = (uint)f2bf(acc[4]) | ((uint)f2bf(acc[5]) << 16);
        o.w = (uint)f2bf(acc[6]) | ((uint)f2bf(acc[7]) << 16);
        ((uint4*)y)[(size_t)i * 32 + sl] = o;
    }
}

// ---------------- fused MLP, GBM=16: grid 625 blocks (~10 waves/CU) ---------
// Block = 16 rows x 256 cols, 4 waves; wave = 16 rows x 64 cols (4 tiles).
// LDS 30 KB -> 5 blocks/CU allowed; ~2.4 resident -> cross-block overlap of
// barrier drains. Layers 0..3 write bf16 hb only; last layer writes f32 out.
__global__ __launch_bounds__(256)
void gemm12_kernel(const ushort* __restrict__ A, const ushort* __restrict__ Wt1,
                   const float* __restrict__ b1, const ushort* __restrict__ Wt2,
                   const float* __restrict__ bnsc, const float* __restrict__ bnsh,
                   float* __restrict__ outF, ushort* __restrict__ outB, int nrows) {
    __shared__ __align__(16) ushort As[GBM][40];
    __shared__ __align__(16) ushort Bs[DIM][40];
    __shared__ __align__(16) ushort Ts[GBM][DIM + 8];
    int tx = threadIdx.x;
    int row0 = blockIdx.x * GBM;
    int wave = tx >> 6, lane = tx & 63, quad = lane >> 4, l16 = lane & 15;
    int wc = wave * 64;
    int srow = tx >> 2;            // 0..63
    int skol = (tx & 3) * 8;       // 0,8,16,24

    f32x4 acc[4];
#pragma unroll
    for (int t = 0; t < 4; ++t) acc[t] = (f32x4){0.f, 0.f, 0.f, 0.f};

    // ---- GEMM1: t = relu(A@W1 + b1) ----
    for (int k0 = 0; k0 < DIM; k0 += 32) {
        if (tx < 64) {             // stage A tile 16x32
            int arow = row0 + srow;
            uint4 av = make_uint4(0u, 0u, 0u, 0u);
            if (arow < nrows) av = *(const uint4*)&A[(size_t)arow * DIM + k0 + skol];
            *(uint4*)&As[srow][skol] = av;
        }
#pragma unroll
        for (int j = 0; j < 4; ++j) {  // stage B tile 256x32
            int r = srow + 64 * j;
            *(uint4*)&Bs[r][skol] = *(const uint4*)&Wt1[(size_t)r * DIM + k0 + skol];
        }
        __syncthreads();
        bf16x8 af = *(const bf16x8*)&As[l16][quad * 8];
#pragma unroll
        for (int tj = 0; tj < 4; ++tj) {
            bf16x8 bf = *(const bf16x8*)&Bs[wc + tj * 16 + l16][quad * 8];
            acc[tj] = __builtin_amdgcn_mfma_f32_16x16x32_bf16(af, bf, acc[tj], 0, 0, 0);
        }
        __syncthreads();
    }
#pragma unroll
    for (int tj = 0; tj < 4; ++tj) {
        int col = wc + tj * 16 + l16;
        float bias = b1[col];
#pragma unroll
        for (int r = 0; r < 4; ++r)
            Ts[quad * 4 + r][col] = f2bf(fmaxf(acc[tj][r] + bias, 0.f));
    }
    __syncthreads();

    // ---- GEMM2: h = relu(bn(t@W2)) ----
#pragma unroll
    for (int t = 0; t < 4; ++t) acc[t] = (f32x4){0.f, 0.f, 0.f, 0.f};
    for (int k0 = 0; k0 < DIM; k0 += 32) {
#pragma unroll
        for (int j = 0; j < 4; ++j) {
            int r = srow + 64 * j;
            *(uint4*)&Bs[r][skol] = *(const uint4*)&Wt2[(size_t)r * DIM + k0 + skol];
        }
        __syncthreads();
        bf16x8 af = *(const bf16x8*)&Ts[l16][k0 + quad * 8];
#pragma unroll
        for (int tj = 0; tj < 4; ++tj) {
            bf16x8 bf = *(const bf16x8*)&Bs[wc + tj * 16 + l16][quad * 8];
            acc[tj] = __builtin_amdgcn_mfma_f32_16x16x32_bf16(af, bf, acc[tj], 0, 0, 0);
        }
        __syncthreads();
    }
#pragma unroll
    for (int tj = 0; tj < 4; ++tj) {
        int col = wc + tj * 16 + l16;
        float s = bnsc[col], sh = bnsh[col];
#pragma unroll
        for (int r = 0; r < 4; ++r) {
            int row = row0 + quad * 4 + r;
            if (row < nrows) {
                float v = fmaxf(acc[tj][r] * s + sh, 0.f);
                if (outF) outF[(size_t)row * DIM + col] = v;
                if (outB) outB[(size_t)row * DIM + col] = f2bf(v);
            }
        }
    }
}

// ---------------- pooling: batch sorted -> per-graph contiguous range -------
__global__ __launch_bounds__(256)
void pool_kernel(const float* __restrict__ hfin, const int* __restrict__ batch,
                 float* __restrict__ out) {
    int g = blockIdx.x;
    int d = threadIdx.x;
    int l = 0, r = N_NODES;
    while (l < r) { int m = (l + r) >> 1; if (batch[m] < g) l = m + 1; else r = m; }
    int lo = l;
    r = N_NODES;
    while (l < r) { int m = (l + r) >> 1; if (batch[m] < g + 1) l = m + 1; else r = m; }
    int hi = l;
    float a0 = 0.f, a1 = 0.f, a2 = 0.f, a3 = 0.f;
    int i = lo;
    for (; i + 4 <= hi; i += 4) {
        a0 += hfin[(size_t)i * DIM + d];
        a1 += hfin[(size_t)(i + 1) * DIM + d];
        a2 += hfin[(size_t)(i + 2) * DIM + d];
        a3 += hfin[(size_t)(i + 3) * DIM + d];
    }
    for (; i < hi; ++i) a0 += hfin[(size_t)i * DIM + d];
    float c = (float)(hi - lo);
    if (c < 1.f) c = 1.f;
    out[g * DIM + d] = ((a0 + a1) + (a2 + a3)) / c;
}

// ---------------- launch ----------------
extern "C" void kernel_launch(void* const* d_in, const int* in_sizes, int n_in,
                              void* d_out, int out_size, void* d_ws, size_t ws_size,
                              hipStream_t stream) {
    const int*   feat_id  = (const int*)d_in[0];
    const int*   ei       = (const int*)d_in[1];
    const int*   batch    = (const int*)d_in[2];
    const float* rwse     = (const float*)d_in[3];
    const int*   in_deg   = (const int*)d_in[4];
    const float* w_val    = (const float*)d_in[5];
    const float* b_val    = (const float*)d_in[6];
    const float* w_rwse   = (const float*)d_in[7];
    const float* b_rwse   = (const float*)d_in[8];
    const float* deg_emb  = (const float*)d_in[9];
    const float* mlp_w1   = (const float*)d_in[10];
    const float* mlp_b1   = (const float*)d_in[11];
    const float* mlp_w2   = (const float*)d_in[12];
    const float* mlp_b2   = (const float*)d_in[13];
    const float* bn_gamma = (const float*)d_in[14];
    const float* bn_beta  = (const float*)d_in[15];
    const float* bn_mean  = (const float*)d_in[16];
    const float* bn_var   = (const float*)d_in[17];
    const float* eps_gin  = (const float*)d_in[18];

    float* out = (float*)d_out;
    float* out_h = out + N_GRAPHS * DIM;   // final h (f32) written by last gemm12

    char* w = (char*)d_ws;
    ushort* hb   = (ushort*)w;                                // N*D bf16
    ushort* y    = hb + (size_t)N_NODES * DIM;                // N*D bf16
    ushort* wt1  = y + (size_t)N_NODES * DIM;                 // L*D*D bf16
    ushort* wt2  = wt1 + (size_t)N_LAYERS * DIM * DIM;        // L*D*D bf16
    int* cnt_arr = (int*)(wt2 + (size_t)N_LAYERS * DIM * DIM); // N
    int* cur     = cnt_arr + N_NODES;                         // N
    int* cs      = cur + N_NODES;                             // E
    float* bnsc  = (float*)(cs + N_EDGES);                    // L*D
    float* bnsh  = bnsc + N_LAYERS * DIM;                     // L*D

    hipMemsetAsync(cnt_arr, 0, N_NODES * sizeof(int), stream);

    setup_kernel<<<11895, 256, 0, stream>>>(
        feat_id, rwse, in_deg, w_val, b_val, w_rwse, b_rwse, deg_emb,
        hb, ei, cnt_arr, mlp_w1, mlp_w2, wt1, wt2,
        bn_gamma, bn_beta, bn_mean, bn_var, mlp_b2, bnsc, bnsh);
    scan_kernel<<<1, 1024, 0, stream>>>(cnt_arr, cur, N_NODES);
    fill_kernel<<<(N_EDGES + 255) / 256, 256, 0, stream>>>(ei, cur, cs);

    int agrid = (N_NODES + 3) / 4;
    int ggrid = (N_NODES + GBM - 1) / GBM;
    for (int l = 0; l < N_LAYERS; ++l) {
        agg_kernel<<<agrid, 256, 0, stream>>>(hb, cur, cs, eps_gin, l, y);
        bool last = (l == N_LAYERS - 1);
        gemm12_kernel<<<ggrid, 256, 0, stream>>>(
            y, wt1 + (size_t)l * DIM * DIM, mlp_b1 + l * DIM,
            wt2 + (size_t)l * DIM * DIM, bnsc + l * DIM, bnsh + l * DIM,
            last ? out_h : nullptr, last ? nullptr : hb, N_NODES);
    }

    pool_kernel<<<N_GRAPHS, 256, 0, stream>>>(out_h, batch, out);
}